// Round 14
// baseline (770.936 us; speedup 1.0000x reference)
//
#include <hip/hip_runtime.h>
#include <hip/hip_bf16.h>

// Shapes (fixed for this problem)
#define B_   16
#define C_   320
#define HW_  1024
#define CO_  256    // conv_out channels
#define NH_  4
#define DKH_ 160
#define QKVC 1344   // 2*640 + 64
#define FCO  1600   // fused conv channels: 256 conv_out + 1344 qkv

using bf16x8 = __attribute__((ext_vector_type(8))) __bf16;
using f32x4  = __attribute__((ext_vector_type(4))) float;

static __device__ __forceinline__ bf16x8 bzero8() {
  bf16x8 r;
#pragma unroll
  for (int j = 0; j < 8; ++j) r[j] = (__bf16)0.0f;
  return r;
}

// ---------------------------------------------------------------------------
// Weight transform (merged): conv_w + qkv_w (fp32 OIHW) -> wt[tap][co][ci]
// ---------------------------------------------------------------------------
__global__ void transform_w2(const float* __restrict__ wc, const float* __restrict__ wq,
                             __bf16* __restrict__ wt) {
  int idx = blockIdx.x * 256 + threadIdx.x;
  if (idx >= FCO * C_) return;
  int ci = idx % C_;
  int co = idx / C_;
  const float* src = (co < CO_) ? (wc + ((size_t)co * C_ + ci) * 9)
                                : (wq + ((size_t)(co - CO_) * C_ + ci) * 9);
#pragma unroll
  for (int t = 0; t < 9; ++t)
    wt[((size_t)t * FCO + co) * C_ + ci] = (__bf16)src[t];
}

// ---------------------------------------------------------------------------
// BN + ReLU + NCHW->NHWC transpose.  x:[B][320][1024] -> y:[B][1024][320] bf16
// ---------------------------------------------------------------------------
template <typename TI>
__global__ __launch_bounds__(256)
void bn_relu_t(const TI* __restrict__ x, const float* __restrict__ g,
               const float* __restrict__ bb, const float* __restrict__ m,
               const float* __restrict__ v, __bf16* __restrict__ y) {
  __shared__ __bf16 tile[32][33];
  int b = blockIdx.z, c0 = blockIdx.y * 32, p0 = blockIdx.x * 32;
#pragma unroll
  for (int i = 0; i < 4; ++i) {
    int cl = threadIdx.y + i * 8;
    int c = c0 + cl;
    int p = p0 + threadIdx.x;
    float scale = g[c] * rsqrtf(v[c] + 1e-5f);
    float val = ((float)x[((size_t)b * C_ + c) * HW_ + p] - m[c]) * scale + bb[c];
    tile[cl][threadIdx.x] = (__bf16)fmaxf(val, 0.0f);
  }
  __syncthreads();
#pragma unroll
  for (int i = 0; i < 4; ++i) {
    int pl = threadIdx.y + i * 8;
    int p = p0 + pl;
    int c = c0 + threadIdx.x;
    y[((size_t)b * HW_ + p) * C_ + c] = tile[threadIdx.x][pl];
  }
}

// ---------------------------------------------------------------------------
// FUSED LDS-tiled implicit-GEMM 3x3 conv (pad=1), MFMA 16x16x32 bf16.
// EXACT R11/R13 known-good: [6][34] act halo, 42.5 KB LDS, 3 blocks/CU,
// global_load_lds W staging (pre-swizzled source), XCD-locality remap.
// (R12 lesson: 4 blocks/CU widens the per-XCD W window past 4 MB L2.)
// ---------------------------------------------------------------------------
template <typename TO>
__global__ __launch_bounds__(256, 3)
void conv3x3_fused(const __bf16* __restrict__ y, const __bf16* __restrict__ wt,
                   const float* __restrict__ bias_c, const float* __restrict__ bias_q,
                   TO* __restrict__ out, const float* __restrict__ resid,
                   __bf16* __restrict__ qt, __bf16* __restrict__ kt,
                   __bf16* __restrict__ vt) {
  __shared__ __align__(16) char act_s[204 * 128];  // (6*34) slots x 128B
  __shared__ __align__(16) char w_s[128 * 128];    // 128 co x 128B

  int tid = threadIdx.x;
  int lane = tid & 63, wv = tid >> 6;
  int lr = lane & 15, lg = lane >> 4;

  int hw_lin = blockIdx.x + 8 * blockIdx.y + 104 * blockIdx.z;
  int xcd = hw_lin & 7, seq = hw_lin >> 3;
  int yhat = seq >> 4;
  int pair = (seq & 15) * 8 + xcd;
  int xhat = pair & 7, zhat = pair >> 3;

  int b = zhat;
  int co_blk = yhat * 128;
  int h0 = xhat * 4;                 // first image row of this p-tile
  int wco = wv >> 1, wp = wv & 1;

  f32x4 zz = {0.f, 0.f, 0.f, 0.f};
  f32x4 acc[4][4];
#pragma unroll
  for (int m = 0; m < 4; ++m)
#pragma unroll
    for (int n = 0; n < 4; ++n) acc[m][n] = zz;

  int rbase[4], cbase[4];
#pragma unroll
  for (int n = 0; n < 4; ++n) {
    int pb = wp * 64 + n * 16 + lr;      // 0..127 within block
    rbase[n] = (pb >> 5) + 1;            // +1 halo offset
    cbase[n] = (pb & 31) + 1;
  }

  const __bf16* ybase = y + (size_t)b * HW_ * C_;

  // W staging source pointers (pre-swizzled global, linear LDS dest)
  int rl8 = lane >> 3;                       // 0..7
  int k8 = lane & 7;
  int swoff = (k8 ^ rl8) * 8;                // pre-swizzled source offset
  const __bf16* wsrc[4];
#pragma unroll
  for (int i = 0; i < 4; ++i) {
    int co = co_blk + i * 32 + wv * 8 + rl8;
    if (co > FCO - 1) co = FCO - 1;          // clamp; epilogue discards OOB co
    wsrc[i] = wt + (size_t)co * C_ + swoff;
  }

  for (int cb = 0; cb < 5; ++cb) {
    int ci0 = cb * 64;
    // ---- stage activation halo (register path; amortized over 9 taps) ----
    for (int g = tid; g < 1632; g += 256) {
      int gi = g & 7, slot = g >> 3;
      int row = slot / 34, col = slot - row * 34;
      int h = h0 + row - 1, c = col - 1;
      bf16x8 val;
      if ((unsigned)h < 32u && (unsigned)c < 32u)
        val = *(const bf16x8*)(ybase + ((size_t)(h * 32 + c)) * C_ + ci0 + gi * 8);
      else
        val = bzero8();
      *(bf16x8*)(act_s + ((slot * 128 + gi * 16) ^ ((col & 7) << 4))) = val;
    }
    for (int tap = 0; tap < 9; ++tap) {
      // ---- stage weight tile [128][64] via global_load_lds ----
      size_t wtap_off = (size_t)tap * FCO * C_ + ci0;
#pragma unroll
      for (int i = 0; i < 4; ++i)
        __builtin_amdgcn_global_load_lds(
            (const __attribute__((address_space(1))) void*)(wsrc[i] + wtap_off),
            (__attribute__((address_space(3))) void*)(w_s + i * 4096 + wv * 1024),
            16, 0, 0);
      __syncthreads();   // drains vmcnt: W (and act at tap==0) ready
      int dh = tap / 3 - 1, dw = tap % 3 - 1;
#pragma unroll
      for (int ks = 0; ks < 2; ++ks) {
        bf16x8 af[4], bfv[4];
#pragma unroll
        for (int m = 0; m < 4; ++m) {
          int co_l = wco * 64 + m * 16 + lr;
          af[m] = *(const bf16x8*)(w_s + ((co_l * 128 + ks * 64 + lg * 16) ^ ((co_l & 7) << 4)));
        }
#pragma unroll
        for (int n = 0; n < 4; ++n) {
          int row = rbase[n] + dh, col = cbase[n] + dw;
          bfv[n] = *(const bf16x8*)(act_s + (((row * 34 + col) * 128 + ks * 64 + lg * 16) ^ ((col & 7) << 4)));
        }
#pragma unroll
        for (int m = 0; m < 4; ++m)
#pragma unroll
          for (int n = 0; n < 4; ++n)
            acc[m][n] = __builtin_amdgcn_mfma_f32_16x16x32_bf16(af[m], bfv[n], acc[m][n], 0, 0, 0);
      }
      __syncthreads();   // compute done -> next stage may overwrite
    }
  }

  const float scaleq = 0.07905694150420949f; // 160^-0.5
  int p_blk = xhat * 128;
#pragma unroll
  for (int m = 0; m < 4; ++m) {
#pragma unroll
    for (int n = 0; n < 4; ++n) {
#pragma unroll
      for (int r = 0; r < 4; ++r) {
        int co = co_blk + wco * 64 + m * 16 + lg * 4 + r;
        if (co >= FCO) continue;
        int p = p_blk + wp * 64 + n * 16 + lr;
        if (co < CO_) {
          float val = acc[m][n][r] + bias_c[co];
          size_t o = ((size_t)b * C_ + co) * HW_ + p;
          if (resid) val += resid[o];
          out[o] = (TO)val;
        } else {
          int qco = co - CO_;
          float val = acc[m][n][r] + bias_q[qco];
          if (qco < 640) {
            int nn = qco / DKH_, d = qco % DKH_;
            qt[(((size_t)b * NH_ + nn) * HW_ + p) * DKH_ + d] = (__bf16)(val * scaleq);
          } else if (qco < 1280) {
            int c2 = qco - 640;
            int nn = c2 / DKH_, d = c2 % DKH_;
            kt[(((size_t)b * NH_ + nn) * HW_ + p) * DKH_ + d] = (__bf16)val;
          } else {
            int c3 = qco - 1280;
            vt[((size_t)b * 64 + c3) * HW_ + p] = (__bf16)val;
          }
        }
      }
    }
  }
}

// ---------------------------------------------------------------------------
// Fused attention, 32 QUERIES PER BLOCK (2 q-tiles of 16), flash-style
// local softmax per wave (256 keys).  Each loaded K fragment feeds BOTH
// q-tiles' MFMAs -> K/rel L2 traffic and block count halve vs 16q blocks.
// Rel rows loaded once, MFMA'd into both tiles' tables.  Softmax/PV per
// tile sequentially, sharing p_lds (intra-wave DS ordering).  2 barriers.
// XCD remap: hw_lin = qb + 32 n + 128 b (2048 blocks); xcd = &7.
// ---------------------------------------------------------------------------
__global__ __launch_bounds__(256)
void attn_kernel(const __bf16* __restrict__ qt, const __bf16* __restrict__ kt,
                 const __bf16* __restrict__ vt, const float* __restrict__ relw,
                 const float* __restrict__ relh, __bf16* __restrict__ attn_out) {
  __shared__ float Rw_lds[2][16][66];
  __shared__ float Rh_lds[2][16][66];
  __shared__ __align__(16) __bf16 p_lds[4][16][136]; // per-wave P half, pad 8
  __shared__ float smax[2][16][4];
  __shared__ float ssum[2][16][4];
  __shared__ float part[2][4][16][16];

  int tid = threadIdx.x;
  int lane = tid & 63, wv = tid >> 6;
  int lr = lane & 15, lg = lane >> 4;

  int hw_lin = blockIdx.x + 32 * blockIdx.y + 128 * blockIdx.z;
  int xcd = hw_lin & 7, s = hw_lin >> 3;
  int qb = s & 31;
  int gg = (s >> 5) * 8 + xcd;
  int n = gg & 3, b = gg >> 2;

  int p0 = qb * 32;
  const size_t qkbase = ((size_t)(b * NH_ + n)) * HW_ * DKH_;

  // Q fragments for both 16-row tiles
  bf16x8 qf[2][5];
#pragma unroll
  for (int g = 0; g < 2; ++g)
#pragma unroll
    for (int ks = 0; ks < 5; ++ks)
      qf[g][ks] = *(const bf16x8*)(qt + qkbase + (size_t)(p0 + g * 16 + lr) * DKH_ + ks * 32 + lg * 8);

  f32x4 zz = {0.f, 0.f, 0.f, 0.f};

  // Rel tables: load each rel row ONCE, MFMA into both tiles' tables.
  {
    int relpos = wv * 16 + lr;
    f32x4 accw[2] = {zz, zz}, acch[2] = {zz, zz};
#pragma unroll
    for (int ks = 0; ks < 5; ++ks) {
      bf16x8 bw, bh;
      if (relpos < 63) {
        const float* pw = relw + (size_t)relpos * DKH_ + ks * 32 + lg * 8;
        const float* ph = relh + (size_t)relpos * DKH_ + ks * 32 + lg * 8;
#pragma unroll
        for (int j = 0; j < 8; ++j) { bw[j] = (__bf16)pw[j]; bh[j] = (__bf16)ph[j]; }
      } else { bw = bzero8(); bh = bzero8(); }
#pragma unroll
      for (int g = 0; g < 2; ++g) {
        accw[g] = __builtin_amdgcn_mfma_f32_16x16x32_bf16(qf[g][ks], bw, accw[g], 0, 0, 0);
        acch[g] = __builtin_amdgcn_mfma_f32_16x16x32_bf16(qf[g][ks], bh, acch[g], 0, 0, 0);
      }
    }
#pragma unroll
    for (int g = 0; g < 2; ++g)
#pragma unroll
      for (int r = 0; r < 4; ++r) {
        Rw_lds[g][lg * 4 + r][wv * 16 + lr] = accw[g][r];
        Rh_lds[g][lg * 4 + r][wv * 16 + lr] = acch[g][r];
      }
  }
  __syncthreads();   // barrier 1: Rw/Rh ready

  // QK^T: each kf feeds both q-tiles
  f32x4 acc[2][16];
#pragma unroll
  for (int g = 0; g < 2; ++g)
#pragma unroll
    for (int t = 0; t < 16; ++t) acc[g][t] = zz;

  int key_base = wv * 256;
  __builtin_amdgcn_s_setprio(1);
#pragma unroll
  for (int t = 0; t < 16; ++t) {
    const __bf16* kp = kt + qkbase + (size_t)(key_base + t * 16 + lr) * DKH_ + lg * 8;
#pragma unroll
    for (int ks = 0; ks < 5; ++ks) {
      bf16x8 kf = *(const bf16x8*)(kp + ks * 32);
      acc[0][t] = __builtin_amdgcn_mfma_f32_16x16x32_bf16(qf[0][ks], kf, acc[0][t], 0, 0, 0);
      acc[1][t] = __builtin_amdgcn_mfma_f32_16x16x32_bf16(qf[1][ks], kf, acc[1][t], 0, 0, 0);
    }
  }
  __builtin_amdgcn_s_setprio(0);

  // V fragments (shared by both tiles)
  bf16x8 vf[8];
  const __bf16* vbase = vt + ((size_t)b * 64 + n * 16 + lr) * HW_ + key_base + lg * 8;
#pragma unroll
  for (int ks = 0; ks < 8; ++ks) vf[ks] = *(const bf16x8*)(vbase + ks * 32);

  // per-tile: rel add, local softmax, 2-pass exp+PV (p_lds shared seq.)
#pragma unroll
  for (int g = 0; g < 2; ++g) {
#pragma unroll
    for (int t = 0; t < 16; ++t) {
      int key = key_base + t * 16 + lr;
      int ky = key & 31, kx = key >> 5;
#pragma unroll
      for (int r = 0; r < 4; ++r) {
        int i = lg * 4 + r;
        int q = p0 + g * 16 + i;
        int yi = q & 31, xi = q >> 5;
        acc[g][t][r] += Rw_lds[g][i][ky - yi + 31] + Rh_lds[g][i][kx - xi + 31];
      }
    }

    float mx[4];
#pragma unroll
    for (int r = 0; r < 4; ++r) {
      float m = acc[g][0][r];
#pragma unroll
      for (int t = 1; t < 16; ++t) m = fmaxf(m, acc[g][t][r]);
#pragma unroll
      for (int msk = 1; msk < 16; msk <<= 1)
        m = fmaxf(m, __shfl_xor(m, msk, 64));
      mx[r] = m;
    }
    if (lr == 0) {
#pragma unroll
      for (int r = 0; r < 4; ++r) smax[g][lg * 4 + r][wv] = mx[r];
    }

    float sm[4] = {0.f, 0.f, 0.f, 0.f};
    f32x4 pv_acc = zz;
#pragma unroll
    for (int half = 0; half < 2; ++half) {
#pragma unroll
      for (int t = half * 8; t < half * 8 + 8; ++t) {
#pragma unroll
        for (int r = 0; r < 4; ++r) {
          float pv = __expf(acc[g][t][r] - mx[r]);
          __bf16 pb = (__bf16)pv;
          sm[r] += (float)pb;             // denominator consistent with bf16 P
          p_lds[wv][lg * 4 + r][(t & 7) * 16 + lr] = pb;
        }
      }
#pragma unroll
      for (int ks = 0; ks < 4; ++ks) {
        bf16x8 pf = *(const bf16x8*)&p_lds[wv][lr][ks * 32 + lg * 8];
        pv_acc = __builtin_amdgcn_mfma_f32_16x16x32_bf16(pf, vf[half * 4 + ks], pv_acc, 0, 0, 0);
      }
    }
#pragma unroll
    for (int r = 0; r < 4; ++r) {
#pragma unroll
      for (int msk = 1; msk < 16; msk <<= 1)
        sm[r] += __shfl_xor(sm[r], msk, 64);
    }
    if (lr == 0) {
#pragma unroll
      for (int r = 0; r < 4; ++r) ssum[g][lg * 4 + r][wv] = sm[r];
    }
#pragma unroll
    for (int r = 0; r < 4; ++r) part[g][wv][lg * 4 + r][lr] = pv_acc[r];
  }
  __syncthreads();   // barrier 2: part/smax/ssum ready

  // epilogue: combine waves per tile, divide, scatter per raw-reshape map
  int i = tid >> 4, dv = tid & 15;
#pragma unroll
  for (int g = 0; g < 2; ++g) {
    float m0 = smax[g][i][0], m1 = smax[g][i][1],
          m2 = smax[g][i][2], m3 = smax[g][i][3];
    float M = fmaxf(fmaxf(m0, m1), fmaxf(m2, m3));
    float e0 = __expf(m0 - M), e1 = __expf(m1 - M),
          e2 = __expf(m2 - M), e3 = __expf(m3 - M);
    float S = ssum[g][i][0] * e0 + ssum[g][i][1] * e1 +
              ssum[g][i][2] * e2 + ssum[g][i][3] * e3;
    float val = (part[g][0][i][dv] * e0 + part[g][1][i][dv] * e1 +
                 part[g][2][i][dv] * e2 + part[g][3][i][dv] * e3) / S;
    int flat = (p0 + g * 16 + i) * 16 + dv;
    attn_out[((size_t)b * 64 + n * 16 + (flat >> 10)) * HW_ + (flat & 1023)] = (__bf16)val;
  }
}

// ---------------------------------------------------------------------------
// 1x1 projection: blockIdx.y = 16-channel quarter -> 4x the blocks/waves.
// ---------------------------------------------------------------------------
template <typename TO>
__global__ __launch_bounds__(256)
void proj1x1(const __bf16* __restrict__ attn, const float* __restrict__ w,
             const float* __restrict__ bias, TO* __restrict__ out,
             const float* __restrict__ resid) {
  __shared__ float wl[16][64];
  int tid = threadIdx.x;
  int cq = blockIdx.y, b = blockIdx.z;
  int p = blockIdx.x * 256 + tid;
  for (int i = tid; i < 1024; i += 256)
    wl[i >> 6][i & 63] = w[(cq * 16 + (i >> 6)) * 64 + (i & 63)];
  __syncthreads();
  float in[64];
#pragma unroll
  for (int c = 0; c < 64; ++c) in[c] = (float)attn[((size_t)b * 64 + c) * HW_ + p];
#pragma unroll
  for (int c = 0; c < 16; ++c) {
    int gc = cq * 16 + c;
    float a = bias[gc];
#pragma unroll
    for (int cc = 0; cc < 64; ++cc) a += wl[c][cc] * in[cc];
    size_t o = ((size_t)b * C_ + 256 + gc) * HW_ + p;
    if (resid) a += resid[o];
    out[o] = (TO)a;
  }
}

// ---------------------------------------------------------------------------
extern "C" void kernel_launch(void* const* d_in, const int* in_sizes, int n_in,
                              void* d_out, int out_size, void* d_ws, size_t ws_size,
                              hipStream_t stream) {
  (void)in_sizes; (void)n_in; (void)out_size;
  const float* x = (const float*)d_in[0];
  const float* bn_g[2]   = {(const float*)d_in[1],  (const float*)d_in[5]};
  const float* bn_b[2]   = {(const float*)d_in[2],  (const float*)d_in[6]};
  const float* bn_m[2]   = {(const float*)d_in[3],  (const float*)d_in[7]};
  const float* bn_v[2]   = {(const float*)d_in[4],  (const float*)d_in[8]};
  const float* conv_w[2] = {(const float*)d_in[9],  (const float*)d_in[17]};
  const float* conv_b[2] = {(const float*)d_in[10], (const float*)d_in[18]};
  const float* qkv_w[2]  = {(const float*)d_in[11], (const float*)d_in[19]};
  const float* qkv_b[2]  = {(const float*)d_in[12], (const float*)d_in[20]};
  const float* attn_w[2] = {(const float*)d_in[13], (const float*)d_in[21]};
  const float* attn_b[2] = {(const float*)d_in[14], (const float*)d_in[22]};
  const float* rel_w[2]  = {(const float*)d_in[15], (const float*)d_in[23]};
  const float* rel_h[2]  = {(const float*)d_in[16], (const float*)d_in[24]};

  char* ws = (char*)d_ws;
  size_t off = 0;
  auto take = [&](size_t bytes) {
    char* p = ws + off;
    off += (bytes + 255) & ~(size_t)255;
    return p;
  };
  __bf16* y_nhwc = (__bf16*)take((size_t)B_ * HW_ * C_ * 2);         // 10.5 MB
  __bf16* qt     = (__bf16*)take((size_t)B_ * NH_ * HW_ * DKH_ * 2); // 21 MB
  __bf16* kt2    = (__bf16*)take((size_t)B_ * NH_ * HW_ * DKH_ * 2); // 21 MB
  __bf16* vt     = (__bf16*)take((size_t)B_ * 64 * HW_ * 2);         // 2 MB
  __bf16* attn_c = (__bf16*)take((size_t)B_ * 64 * HW_ * 2);         // 2 MB
  __bf16* l1out  = (__bf16*)take((size_t)B_ * C_ * HW_ * 2);         // 10.5 MB
  __bf16* wt_s   = (__bf16*)take((size_t)9 * FCO * C_ * 2);          // 9.2 MB (fused)
  if (ws_size < off) return;  // diagnostic: finite-error failure => ws too small

  for (int l = 0; l < 2; ++l) {
    const float* resid = (l == 0) ? nullptr : x;

    if (l == 0)
      bn_relu_t<float><<<dim3(32, 10, 16), dim3(32, 8), 0, stream>>>(
          x, bn_g[l], bn_b[l], bn_m[l], bn_v[l], y_nhwc);
    else
      bn_relu_t<__bf16><<<dim3(32, 10, 16), dim3(32, 8), 0, stream>>>(
          l1out, bn_g[l], bn_b[l], bn_m[l], bn_v[l], y_nhwc);

    transform_w2<<<(FCO * C_ + 255) / 256, 256, 0, stream>>>(conv_w[l], qkv_w[l], wt_s);

    if (l == 0)
      conv3x3_fused<__bf16><<<dim3(8, 13, 16), 256, 0, stream>>>(
          y_nhwc, wt_s, conv_b[l], qkv_b[l], l1out, nullptr, qt, kt2, vt);
    else
      conv3x3_fused<float><<<dim3(8, 13, 16), 256, 0, stream>>>(
          y_nhwc, wt_s, conv_b[l], qkv_b[l], (float*)d_out, resid, qt, kt2, vt);

    attn_kernel<<<dim3(32, NH_, 16), 256, 0, stream>>>(
        qt, kt2, vt, rel_w[l], rel_h[l], attn_c);

    if (l == 0)
      proj1x1<__bf16><<<dim3(4, 4, 16), 256, 0, stream>>>(
          attn_c, attn_w[l], attn_b[l], l1out, nullptr);
    else
      proj1x1<float><<<dim3(4, 4, 16), 256, 0, stream>>>(
          attn_c, attn_w[l], attn_b[l], (float*)d_out, resid);
  }
}

// Round 15
// 727.361 us; speedup vs baseline: 1.0599x; 1.0599x over previous
//
#include <hip/hip_runtime.h>
#include <hip/hip_bf16.h>

// Shapes (fixed for this problem)
#define B_   16
#define C_   320
#define HW_  1024
#define CO_  256    // conv_out channels
#define NH_  4
#define DKH_ 160
#define QKVC 1344   // 2*640 + 64
#define FCO  1600   // fused conv channels: 256 conv_out + 1344 qkv

using bf16x8 = __attribute__((ext_vector_type(8))) __bf16;
using f32x4  = __attribute__((ext_vector_type(4))) float;

static __device__ __forceinline__ bf16x8 bzero8() {
  bf16x8 r;
#pragma unroll
  for (int j = 0; j < 8; ++j) r[j] = (__bf16)0.0f;
  return r;
}

// ---------------------------------------------------------------------------
// Weight transform (merged): conv_w + qkv_w (fp32 OIHW) -> wt[tap][co][ci]
// ---------------------------------------------------------------------------
__global__ void transform_w2(const float* __restrict__ wc, const float* __restrict__ wq,
                             __bf16* __restrict__ wt) {
  int idx = blockIdx.x * 256 + threadIdx.x;
  if (idx >= FCO * C_) return;
  int ci = idx % C_;
  int co = idx / C_;
  const float* src = (co < CO_) ? (wc + ((size_t)co * C_ + ci) * 9)
                                : (wq + ((size_t)(co - CO_) * C_ + ci) * 9);
#pragma unroll
  for (int t = 0; t < 9; ++t)
    wt[((size_t)t * FCO + co) * C_ + ci] = (__bf16)src[t];
}

// ---------------------------------------------------------------------------
// BN + ReLU + NCHW->NHWC transpose.  x:[B][320][1024] -> y:[B][1024][320] bf16
// ---------------------------------------------------------------------------
template <typename TI>
__global__ __launch_bounds__(256)
void bn_relu_t(const TI* __restrict__ x, const float* __restrict__ g,
               const float* __restrict__ bb, const float* __restrict__ m,
               const float* __restrict__ v, __bf16* __restrict__ y) {
  __shared__ __bf16 tile[32][33];
  int b = blockIdx.z, c0 = blockIdx.y * 32, p0 = blockIdx.x * 32;
#pragma unroll
  for (int i = 0; i < 4; ++i) {
    int cl = threadIdx.y + i * 8;
    int c = c0 + cl;
    int p = p0 + threadIdx.x;
    float scale = g[c] * rsqrtf(v[c] + 1e-5f);
    float val = ((float)x[((size_t)b * C_ + c) * HW_ + p] - m[c]) * scale + bb[c];
    tile[cl][threadIdx.x] = (__bf16)fmaxf(val, 0.0f);
  }
  __syncthreads();
#pragma unroll
  for (int i = 0; i < 4; ++i) {
    int pl = threadIdx.y + i * 8;
    int p = p0 + pl;
    int c = c0 + threadIdx.x;
    y[((size_t)b * HW_ + p) * C_ + c] = tile[threadIdx.x][pl];
  }
}

// ---------------------------------------------------------------------------
// FUSED LDS-tiled implicit-GEMM 3x3 conv (pad=1), MFMA 16x16x32 bf16.
// R13 envelope (single W buffer, 42.5 KB LDS, 3 blocks/CU, XCD remap) with
// REORDERED per-tap phase (this round's single change):
//   A: barrier (W(t)+act visible; drains vmcnt issued BEFORE last MFMA phase)
//   read af (w_s -> regs); C: barrier (cheap, lgkm-only drain)
//   issue W(t+1) stage (safe overwrite); bfv reads + 32 MFMA (hides stage)
// Act restage gets a dedicated barrier at chunk boundaries.
// ---------------------------------------------------------------------------
template <typename TO>
__global__ __launch_bounds__(256, 3)
void conv3x3_fused(const __bf16* __restrict__ y, const __bf16* __restrict__ wt,
                   const float* __restrict__ bias_c, const float* __restrict__ bias_q,
                   TO* __restrict__ out, const float* __restrict__ resid,
                   __bf16* __restrict__ qt, __bf16* __restrict__ kt,
                   __bf16* __restrict__ vt) {
  __shared__ __align__(16) char act_s[204 * 128];  // (6*34) slots x 128B
  __shared__ __align__(16) char w_s[128 * 128];    // 128 co x 128B

  int tid = threadIdx.x;
  int lane = tid & 63, wv = tid >> 6;
  int lr = lane & 15, lg = lane >> 4;

  int hw_lin = blockIdx.x + 8 * blockIdx.y + 104 * blockIdx.z;
  int xcd = hw_lin & 7, seq = hw_lin >> 3;
  int yhat = seq >> 4;
  int pair = (seq & 15) * 8 + xcd;
  int xhat = pair & 7, zhat = pair >> 3;

  int b = zhat;
  int co_blk = yhat * 128;
  int h0 = xhat * 4;                 // first image row of this p-tile
  int wco = wv >> 1, wp = wv & 1;

  f32x4 zz = {0.f, 0.f, 0.f, 0.f};
  f32x4 acc[4][4];
#pragma unroll
  for (int m = 0; m < 4; ++m)
#pragma unroll
    for (int n = 0; n < 4; ++n) acc[m][n] = zz;

  int rbase[4], cbase[4];
#pragma unroll
  for (int n = 0; n < 4; ++n) {
    int pb = wp * 64 + n * 16 + lr;      // 0..127 within block
    rbase[n] = (pb >> 5) + 1;            // +1 halo offset
    cbase[n] = (pb & 31) + 1;
  }

  const __bf16* ybase = y + (size_t)b * HW_ * C_;

  // W staging source pointers (pre-swizzled global, linear LDS dest)
  int rl8 = lane >> 3;                       // 0..7
  int k8 = lane & 7;
  int swoff = (k8 ^ rl8) * 8;                // pre-swizzled source offset
  const __bf16* wsrc[4];
#pragma unroll
  for (int i = 0; i < 4; ++i) {
    int co = co_blk + i * 32 + wv * 8 + rl8;
    if (co > FCO - 1) co = FCO - 1;          // clamp; epilogue discards OOB co
    wsrc[i] = wt + (size_t)co * C_ + swoff;
  }

  auto stage_W = [&](int tap, int chunk) {
    size_t woff = (size_t)tap * FCO * C_ + chunk * 64;
#pragma unroll
    for (int i = 0; i < 4; ++i)
      __builtin_amdgcn_global_load_lds(
          (const __attribute__((address_space(1))) void*)(wsrc[i] + woff),
          (__attribute__((address_space(3))) void*)(w_s + i * 4096 + wv * 1024),
          16, 0, 0);
  };
  auto stage_act = [&](int chunk) {
    int ci0 = chunk * 64;
    for (int g = tid; g < 1632; g += 256) {
      int gi = g & 7, slot = g >> 3;
      int row = slot / 34, col = slot - row * 34;
      int h = h0 + row - 1, c = col - 1;
      bf16x8 val;
      if ((unsigned)h < 32u && (unsigned)c < 32u)
        val = *(const bf16x8*)(ybase + ((size_t)(h * 32 + c)) * C_ + ci0 + gi * 8);
      else
        val = bzero8();
      *(bf16x8*)(act_s + ((slot * 128 + gi * 16) ^ ((col & 7) << 4))) = val;
    }
  };

  // prologue: act chunk 0 + W(tap0,chunk0) in flight; first barrier A drains
  stage_act(0);
  stage_W(0, 0);

  for (int cb = 0; cb < 5; ++cb) {
    for (int tap = 0; tap < 9; ++tap) {
      __syncthreads();   // A: W(t)+act visible (drain was covered by MFMAs)
      bf16x8 af[2][4];
#pragma unroll
      for (int ks = 0; ks < 2; ++ks)
#pragma unroll
        for (int m = 0; m < 4; ++m) {
          int co_l = wco * 64 + m * 16 + lr;
          af[ks][m] = *(const bf16x8*)(w_s + ((co_l * 128 + ks * 64 + lg * 16) ^ ((co_l & 7) << 4)));
        }
      __syncthreads();   // C: all waves' w_s reads done (lgkm-only drain)
      if (!(cb == 4 && tap == 8))
        stage_W(tap == 8 ? 0 : tap + 1, tap == 8 ? cb + 1 : cb);
      int dh = tap / 3 - 1, dw = tap % 3 - 1;
#pragma unroll
      for (int ks = 0; ks < 2; ++ks) {
        bf16x8 bfv[4];
#pragma unroll
        for (int n = 0; n < 4; ++n) {
          int row = rbase[n] + dh, col = cbase[n] + dw;
          bfv[n] = *(const bf16x8*)(act_s + (((row * 34 + col) * 128 + ks * 64 + lg * 16) ^ ((col & 7) << 4)));
        }
#pragma unroll
        for (int m = 0; m < 4; ++m)
#pragma unroll
          for (int n = 0; n < 4; ++n)
            acc[m][n] = __builtin_amdgcn_mfma_f32_16x16x32_bf16(af[ks][m], bfv[n], acc[m][n], 0, 0, 0);
      }
      if (tap == 8 && cb < 4) {
        __syncthreads();       // all waves' act_s reads done
        stage_act(cb + 1);     // drains at next iteration's barrier A
      }
    }
  }

  const float scaleq = 0.07905694150420949f; // 160^-0.5
  int p_blk = xhat * 128;
#pragma unroll
  for (int m = 0; m < 4; ++m) {
#pragma unroll
    for (int n = 0; n < 4; ++n) {
#pragma unroll
      for (int r = 0; r < 4; ++r) {
        int co = co_blk + wco * 64 + m * 16 + lg * 4 + r;
        if (co >= FCO) continue;
        int p = p_blk + wp * 64 + n * 16 + lr;
        if (co < CO_) {
          float val = acc[m][n][r] + bias_c[co];
          size_t o = ((size_t)b * C_ + co) * HW_ + p;
          if (resid) val += resid[o];
          out[o] = (TO)val;
        } else {
          int qco = co - CO_;
          float val = acc[m][n][r] + bias_q[qco];
          if (qco < 640) {
            int nn = qco / DKH_, d = qco % DKH_;
            qt[(((size_t)b * NH_ + nn) * HW_ + p) * DKH_ + d] = (__bf16)(val * scaleq);
          } else if (qco < 1280) {
            int c2 = qco - 640;
            int nn = c2 / DKH_, d = c2 % DKH_;
            kt[(((size_t)b * NH_ + nn) * HW_ + p) * DKH_ + d] = (__bf16)val;
          } else {
            int c3 = qco - 1280;
            vt[((size_t)b * 64 + c3) * HW_ + p] = (__bf16)val;
          }
        }
      }
    }
  }
}

// ---------------------------------------------------------------------------
// Fused attention per (b, head, 16-query block) — flash-style local softmax.
// EXACT R13 known-good (16 queries/block, 2-pass PV, XCD remap).
// ---------------------------------------------------------------------------
__global__ __launch_bounds__(256)
void attn_kernel(const __bf16* __restrict__ qt, const __bf16* __restrict__ kt,
                 const __bf16* __restrict__ vt, const float* __restrict__ relw,
                 const float* __restrict__ relh, __bf16* __restrict__ attn_out) {
  __shared__ float Rw_lds[16][66];
  __shared__ float Rh_lds[16][66];
  __shared__ __align__(16) __bf16 p_lds[4][16][136]; // per-wave P half, pad 8
  __shared__ float smax[16][4];
  __shared__ float ssum[16][4];
  __shared__ float part[4][16][16];

  int tid = threadIdx.x;
  int lane = tid & 63, wv = tid >> 6;
  int lr = lane & 15, lg = lane >> 4;

  int hw_lin = blockIdx.x + 64 * blockIdx.y + 256 * blockIdx.z;
  int xcd = hw_lin & 7, s = hw_lin >> 3;
  int qb = s & 63;
  int g = (s >> 6) * 8 + xcd;
  int n = g & 3, b = g >> 2;

  int p0 = qb * 16;
  const size_t qkbase = ((size_t)(b * NH_ + n)) * HW_ * DKH_;

  bf16x8 qf[5];
#pragma unroll
  for (int ks = 0; ks < 5; ++ks)
    qf[ks] = *(const bf16x8*)(qt + qkbase + (size_t)(p0 + lr) * DKH_ + ks * 32 + lg * 8);

  f32x4 zz = {0.f, 0.f, 0.f, 0.f};

  {
    int relpos = wv * 16 + lr;
    f32x4 accw = zz, acch = zz;
#pragma unroll
    for (int ks = 0; ks < 5; ++ks) {
      bf16x8 bw, bh;
      if (relpos < 63) {
        const float* pw = relw + (size_t)relpos * DKH_ + ks * 32 + lg * 8;
        const float* ph = relh + (size_t)relpos * DKH_ + ks * 32 + lg * 8;
#pragma unroll
        for (int j = 0; j < 8; ++j) { bw[j] = (__bf16)pw[j]; bh[j] = (__bf16)ph[j]; }
      } else { bw = bzero8(); bh = bzero8(); }
      accw = __builtin_amdgcn_mfma_f32_16x16x32_bf16(qf[ks], bw, accw, 0, 0, 0);
      acch = __builtin_amdgcn_mfma_f32_16x16x32_bf16(qf[ks], bh, acch, 0, 0, 0);
    }
#pragma unroll
    for (int r = 0; r < 4; ++r) {
      Rw_lds[lg * 4 + r][wv * 16 + lr] = accw[r];
      Rh_lds[lg * 4 + r][wv * 16 + lr] = acch[r];
    }
  }
  __syncthreads();   // barrier 1: Rw/Rh ready

  f32x4 acc[16];
#pragma unroll
  for (int t = 0; t < 16; ++t) acc[t] = zz;

  int key_base = wv * 256;
  __builtin_amdgcn_s_setprio(1);
#pragma unroll
  for (int t = 0; t < 16; ++t) {
    const __bf16* kp = kt + qkbase + (size_t)(key_base + t * 16 + lr) * DKH_ + lg * 8;
#pragma unroll
    for (int ks = 0; ks < 5; ++ks) {
      bf16x8 kf = *(const bf16x8*)(kp + ks * 32);
      acc[t] = __builtin_amdgcn_mfma_f32_16x16x32_bf16(qf[ks], kf, acc[t], 0, 0, 0);
    }
  }
  __builtin_amdgcn_s_setprio(0);

  bf16x8 vf[8];
  const __bf16* vbase = vt + ((size_t)b * 64 + n * 16 + lr) * HW_ + key_base + lg * 8;
#pragma unroll
  for (int ks = 0; ks < 8; ++ks) vf[ks] = *(const bf16x8*)(vbase + ks * 32);

#pragma unroll
  for (int t = 0; t < 16; ++t) {
    int key = key_base + t * 16 + lr;
    int ky = key & 31, kx = key >> 5;
#pragma unroll
    for (int r = 0; r < 4; ++r) {
      int i = lg * 4 + r;
      int yi = (p0 + i) & 31, xi = (p0 + i) >> 5;
      acc[t][r] += Rw_lds[i][ky - yi + 31] + Rh_lds[i][kx - xi + 31];
    }
  }

  float mx[4];
#pragma unroll
  for (int r = 0; r < 4; ++r) {
    float m = acc[0][r];
#pragma unroll
    for (int t = 1; t < 16; ++t) m = fmaxf(m, acc[t][r]);
#pragma unroll
    for (int msk = 1; msk < 16; msk <<= 1)
      m = fmaxf(m, __shfl_xor(m, msk, 64));
    mx[r] = m;
  }
  if (lr == 0) {
#pragma unroll
    for (int r = 0; r < 4; ++r) smax[lg * 4 + r][wv] = mx[r];
  }

  // 2-pass exp + PV: keys [0,128) then [128,256), sharing the half-size p_lds
  float sm[4] = {0.f, 0.f, 0.f, 0.f};
  f32x4 pv_acc = zz;
#pragma unroll
  for (int half = 0; half < 2; ++half) {
#pragma unroll
    for (int t = half * 8; t < half * 8 + 8; ++t) {
#pragma unroll
      for (int r = 0; r < 4; ++r) {
        float pv = __expf(acc[t][r] - mx[r]);
        __bf16 pb = (__bf16)pv;
        sm[r] += (float)pb;               // denominator consistent with bf16 P
        p_lds[wv][lg * 4 + r][(t & 7) * 16 + lr] = pb;
      }
    }
#pragma unroll
    for (int ks = 0; ks < 4; ++ks) {
      bf16x8 pf = *(const bf16x8*)&p_lds[wv][lr][ks * 32 + lg * 8];
      pv_acc = __builtin_amdgcn_mfma_f32_16x16x32_bf16(pf, vf[half * 4 + ks], pv_acc, 0, 0, 0);
    }
  }
#pragma unroll
  for (int r = 0; r < 4; ++r) {
#pragma unroll
    for (int msk = 1; msk < 16; msk <<= 1)
      sm[r] += __shfl_xor(sm[r], msk, 64);
  }
  if (lr == 0) {
#pragma unroll
    for (int r = 0; r < 4; ++r) ssum[lg * 4 + r][wv] = sm[r];
  }

#pragma unroll
  for (int r = 0; r < 4; ++r) part[wv][lg * 4 + r][lr] = pv_acc[r];
  __syncthreads();   // barrier 2: part/smax/ssum ready

  int i = tid >> 4, dv = tid & 15;
  float m0 = smax[i][0], m1 = smax[i][1], m2 = smax[i][2], m3 = smax[i][3];
  float M = fmaxf(fmaxf(m0, m1), fmaxf(m2, m3));
  float e0 = __expf(m0 - M), e1 = __expf(m1 - M),
        e2 = __expf(m2 - M), e3 = __expf(m3 - M);
  float S = ssum[i][0] * e0 + ssum[i][1] * e1 + ssum[i][2] * e2 + ssum[i][3] * e3;
  float val = (part[0][i][dv] * e0 + part[1][i][dv] * e1 +
               part[2][i][dv] * e2 + part[3][i][dv] * e3) / S;
  int flat = (p0 + i) * 16 + dv;
  attn_out[((size_t)b * 64 + n * 16 + (flat >> 10)) * HW_ + (flat & 1023)] = (__bf16)val;
}

// ---------------------------------------------------------------------------
// 1x1 projection: blockIdx.y = 16-channel quarter -> 4x the blocks/waves.
// ---------------------------------------------------------------------------
template <typename TO>
__global__ __launch_bounds__(256)
void proj1x1(const __bf16* __restrict__ attn, const float* __restrict__ w,
             const float* __restrict__ bias, TO* __restrict__ out,
             const float* __restrict__ resid) {
  __shared__ float wl[16][64];
  int tid = threadIdx.x;
  int cq = blockIdx.y, b = blockIdx.z;
  int p = blockIdx.x * 256 + tid;
  for (int i = tid; i < 1024; i += 256)
    wl[i >> 6][i & 63] = w[(cq * 16 + (i >> 6)) * 64 + (i & 63)];
  __syncthreads();
  float in[64];
#pragma unroll
  for (int c = 0; c < 64; ++c) in[c] = (float)attn[((size_t)b * 64 + c) * HW_ + p];
#pragma unroll
  for (int c = 0; c < 16; ++c) {
    int gc = cq * 16 + c;
    float a = bias[gc];
#pragma unroll
    for (int cc = 0; cc < 64; ++cc) a += wl[c][cc] * in[cc];
    size_t o = ((size_t)b * C_ + 256 + gc) * HW_ + p;
    if (resid) a += resid[o];
    out[o] = (TO)a;
  }
}

// ---------------------------------------------------------------------------
extern "C" void kernel_launch(void* const* d_in, const int* in_sizes, int n_in,
                              void* d_out, int out_size, void* d_ws, size_t ws_size,
                              hipStream_t stream) {
  (void)in_sizes; (void)n_in; (void)out_size;
  const float* x = (const float*)d_in[0];
  const float* bn_g[2]   = {(const float*)d_in[1],  (const float*)d_in[5]};
  const float* bn_b[2]   = {(const float*)d_in[2],  (const float*)d_in[6]};
  const float* bn_m[2]   = {(const float*)d_in[3],  (const float*)d_in[7]};
  const float* bn_v[2]   = {(const float*)d_in[4],  (const float*)d_in[8]};
  const float* conv_w[2] = {(const float*)d_in[9],  (const float*)d_in[17]};
  const float* conv_b[2] = {(const float*)d_in[10], (const float*)d_in[18]};
  const float* qkv_w[2]  = {(const float*)d_in[11], (const float*)d_in[19]};
  const float* qkv_b[2]  = {(const float*)d_in[12], (const float*)d_in[20]};
  const float* attn_w[2] = {(const float*)d_in[13], (const float*)d_in[21]};
  const float* attn_b[2] = {(const float*)d_in[14], (const float*)d_in[22]};
  const float* rel_w[2]  = {(const float*)d_in[15], (const float*)d_in[23]};
  const float* rel_h[2]  = {(const float*)d_in[16], (const float*)d_in[24]};

  char* ws = (char*)d_ws;
  size_t off = 0;
  auto take = [&](size_t bytes) {
    char* p = ws + off;
    off += (bytes + 255) & ~(size_t)255;
    return p;
  };
  __bf16* y_nhwc = (__bf16*)take((size_t)B_ * HW_ * C_ * 2);         // 10.5 MB
  __bf16* qt     = (__bf16*)take((size_t)B_ * NH_ * HW_ * DKH_ * 2); // 21 MB
  __bf16* kt2    = (__bf16*)take((size_t)B_ * NH_ * HW_ * DKH_ * 2); // 21 MB
  __bf16* vt     = (__bf16*)take((size_t)B_ * 64 * HW_ * 2);         // 2 MB
  __bf16* attn_c = (__bf16*)take((size_t)B_ * 64 * HW_ * 2);         // 2 MB
  __bf16* l1out  = (__bf16*)take((size_t)B_ * C_ * HW_ * 2);         // 10.5 MB
  __bf16* wt_s   = (__bf16*)take((size_t)9 * FCO * C_ * 2);          // 9.2 MB (fused)
  if (ws_size < off) return;  // diagnostic: finite-error failure => ws too small

  for (int l = 0; l < 2; ++l) {
    const float* resid = (l == 0) ? nullptr : x;

    if (l == 0)
      bn_relu_t<float><<<dim3(32, 10, 16), dim3(32, 8), 0, stream>>>(
          x, bn_g[l], bn_b[l], bn_m[l], bn_v[l], y_nhwc);
    else
      bn_relu_t<__bf16><<<dim3(32, 10, 16), dim3(32, 8), 0, stream>>>(
          l1out, bn_g[l], bn_b[l], bn_m[l], bn_v[l], y_nhwc);

    transform_w2<<<(FCO * C_ + 255) / 256, 256, 0, stream>>>(conv_w[l], qkv_w[l], wt_s);

    if (l == 0)
      conv3x3_fused<__bf16><<<dim3(8, 13, 16), 256, 0, stream>>>(
          y_nhwc, wt_s, conv_b[l], qkv_b[l], l1out, nullptr, qt, kt2, vt);
    else
      conv3x3_fused<float><<<dim3(8, 13, 16), 256, 0, stream>>>(
          y_nhwc, wt_s, conv_b[l], qkv_b[l], (float*)d_out, resid, qt, kt2, vt);

    attn_kernel<<<dim3(64, NH_, 16), 256, 0, stream>>>(
        qt, kt2, vt, rel_w[l], rel_h[l], attn_c);

    if (l == 0)
      proj1x1<__bf16><<<dim3(4, 4, 16), 256, 0, stream>>>(
          attn_c, attn_w[l], attn_b[l], l1out, nullptr);
    else
      proj1x1<float><<<dim3(4, 4, 16), 256, 0, stream>>>(
          attn_c, attn_w[l], attn_b[l], (float*)d_out, resid);
  }
}

// Round 16
// 643.014 us; speedup vs baseline: 1.1989x; 1.1312x over previous
//
#include <hip/hip_runtime.h>
#include <hip/hip_bf16.h>

// Shapes (fixed for this problem)
#define B_   16
#define C_   320
#define HW_  1024
#define CO_  256    // conv_out channels
#define NH_  4
#define DKH_ 160
#define QKVC 1344   // 2*640 + 64
#define FCO  1600   // fused conv channels: 256 conv_out + 1344 qkv

using bf16x8 = __attribute__((ext_vector_type(8))) __bf16;
using f32x4  = __attribute__((ext_vector_type(4))) float;

static __device__ __forceinline__ bf16x8 bzero8() {
  bf16x8 r;
#pragma unroll
  for (int j = 0; j < 8; ++j) r[j] = (__bf16)0.0f;
  return r;
}

// ---------------------------------------------------------------------------
// Weight transform (merged): conv_w + qkv_w (fp32 OIHW) -> wt[tap][co][ci]
// ---------------------------------------------------------------------------
__global__ void transform_w2(const float* __restrict__ wc, const float* __restrict__ wq,
                             __bf16* __restrict__ wt) {
  int idx = blockIdx.x * 256 + threadIdx.x;
  if (idx >= FCO * C_) return;
  int ci = idx % C_;
  int co = idx / C_;
  const float* src = (co < CO_) ? (wc + ((size_t)co * C_ + ci) * 9)
                                : (wq + ((size_t)(co - CO_) * C_ + ci) * 9);
#pragma unroll
  for (int t = 0; t < 9; ++t)
    wt[((size_t)t * FCO + co) * C_ + ci] = (__bf16)src[t];
}

// rel tables fp32 [63][160] -> bf16 (both w and h), 10080 elems each
__global__ void transform_rel(const float* __restrict__ rw, const float* __restrict__ rh,
                              __bf16* __restrict__ rwb, __bf16* __restrict__ rhb) {
  int idx = blockIdx.x * 256 + threadIdx.x;
  if (idx >= 63 * DKH_) return;
  rwb[idx] = (__bf16)rw[idx];
  rhb[idx] = (__bf16)rh[idx];
}

// ---------------------------------------------------------------------------
// BN + ReLU + NCHW->NHWC transpose.  x:[B][320][1024] -> y:[B][1024][320] bf16
// ---------------------------------------------------------------------------
template <typename TI>
__global__ __launch_bounds__(256)
void bn_relu_t(const TI* __restrict__ x, const float* __restrict__ g,
               const float* __restrict__ bb, const float* __restrict__ m,
               const float* __restrict__ v, __bf16* __restrict__ y) {
  __shared__ __bf16 tile[32][33];
  int b = blockIdx.z, c0 = blockIdx.y * 32, p0 = blockIdx.x * 32;
#pragma unroll
  for (int i = 0; i < 4; ++i) {
    int cl = threadIdx.y + i * 8;
    int c = c0 + cl;
    int p = p0 + threadIdx.x;
    float scale = g[c] * rsqrtf(v[c] + 1e-5f);
    float val = ((float)x[((size_t)b * C_ + c) * HW_ + p] - m[c]) * scale + bb[c];
    tile[cl][threadIdx.x] = (__bf16)fmaxf(val, 0.0f);
  }
  __syncthreads();
#pragma unroll
  for (int i = 0; i < 4; ++i) {
    int pl = threadIdx.y + i * 8;
    int p = p0 + pl;
    int c = c0 + threadIdx.x;
    y[((size_t)b * HW_ + p) * C_ + c] = tile[threadIdx.x][pl];
  }
}

// ---------------------------------------------------------------------------
// FUSED LDS-tiled implicit-GEMM 3x3 conv (pad=1), MFMA 16x16x32 bf16.
// EXACT R15 known-good (reordered per-tap phase, 212 us/layer).
// ---------------------------------------------------------------------------
template <typename TO>
__global__ __launch_bounds__(256, 3)
void conv3x3_fused(const __bf16* __restrict__ y, const __bf16* __restrict__ wt,
                   const float* __restrict__ bias_c, const float* __restrict__ bias_q,
                   TO* __restrict__ out, const float* __restrict__ resid,
                   __bf16* __restrict__ qt, __bf16* __restrict__ kt,
                   __bf16* __restrict__ vt) {
  __shared__ __align__(16) char act_s[204 * 128];  // (6*34) slots x 128B
  __shared__ __align__(16) char w_s[128 * 128];    // 128 co x 128B

  int tid = threadIdx.x;
  int lane = tid & 63, wv = tid >> 6;
  int lr = lane & 15, lg = lane >> 4;

  int hw_lin = blockIdx.x + 8 * blockIdx.y + 104 * blockIdx.z;
  int xcd = hw_lin & 7, seq = hw_lin >> 3;
  int yhat = seq >> 4;
  int pair = (seq & 15) * 8 + xcd;
  int xhat = pair & 7, zhat = pair >> 3;

  int b = zhat;
  int co_blk = yhat * 128;
  int h0 = xhat * 4;                 // first image row of this p-tile
  int wco = wv >> 1, wp = wv & 1;

  f32x4 zz = {0.f, 0.f, 0.f, 0.f};
  f32x4 acc[4][4];
#pragma unroll
  for (int m = 0; m < 4; ++m)
#pragma unroll
    for (int n = 0; n < 4; ++n) acc[m][n] = zz;

  int rbase[4], cbase[4];
#pragma unroll
  for (int n = 0; n < 4; ++n) {
    int pb = wp * 64 + n * 16 + lr;      // 0..127 within block
    rbase[n] = (pb >> 5) + 1;            // +1 halo offset
    cbase[n] = (pb & 31) + 1;
  }

  const __bf16* ybase = y + (size_t)b * HW_ * C_;

  // W staging source pointers (pre-swizzled global, linear LDS dest)
  int rl8 = lane >> 3;                       // 0..7
  int k8 = lane & 7;
  int swoff = (k8 ^ rl8) * 8;                // pre-swizzled source offset
  const __bf16* wsrc[4];
#pragma unroll
  for (int i = 0; i < 4; ++i) {
    int co = co_blk + i * 32 + wv * 8 + rl8;
    if (co > FCO - 1) co = FCO - 1;          // clamp; epilogue discards OOB co
    wsrc[i] = wt + (size_t)co * C_ + swoff;
  }

  auto stage_W = [&](int tap, int chunk) {
    size_t woff = (size_t)tap * FCO * C_ + chunk * 64;
#pragma unroll
    for (int i = 0; i < 4; ++i)
      __builtin_amdgcn_global_load_lds(
          (const __attribute__((address_space(1))) void*)(wsrc[i] + woff),
          (__attribute__((address_space(3))) void*)(w_s + i * 4096 + wv * 1024),
          16, 0, 0);
  };
  auto stage_act = [&](int chunk) {
    int ci0 = chunk * 64;
    for (int g = tid; g < 1632; g += 256) {
      int gi = g & 7, slot = g >> 3;
      int row = slot / 34, col = slot - row * 34;
      int h = h0 + row - 1, c = col - 1;
      bf16x8 val;
      if ((unsigned)h < 32u && (unsigned)c < 32u)
        val = *(const bf16x8*)(ybase + ((size_t)(h * 32 + c)) * C_ + ci0 + gi * 8);
      else
        val = bzero8();
      *(bf16x8*)(act_s + ((slot * 128 + gi * 16) ^ ((col & 7) << 4))) = val;
    }
  };

  // prologue: act chunk 0 + W(tap0,chunk0) in flight; first barrier A drains
  stage_act(0);
  stage_W(0, 0);

  for (int cb = 0; cb < 5; ++cb) {
    for (int tap = 0; tap < 9; ++tap) {
      __syncthreads();   // A: W(t)+act visible (drain was covered by MFMAs)
      bf16x8 af[2][4];
#pragma unroll
      for (int ks = 0; ks < 2; ++ks)
#pragma unroll
        for (int m = 0; m < 4; ++m) {
          int co_l = wco * 64 + m * 16 + lr;
          af[ks][m] = *(const bf16x8*)(w_s + ((co_l * 128 + ks * 64 + lg * 16) ^ ((co_l & 7) << 4)));
        }
      __syncthreads();   // C: all waves' w_s reads done (lgkm-only drain)
      if (!(cb == 4 && tap == 8))
        stage_W(tap == 8 ? 0 : tap + 1, tap == 8 ? cb + 1 : cb);
      int dh = tap / 3 - 1, dw = tap % 3 - 1;
#pragma unroll
      for (int ks = 0; ks < 2; ++ks) {
        bf16x8 bfv[4];
#pragma unroll
        for (int n = 0; n < 4; ++n) {
          int row = rbase[n] + dh, col = cbase[n] + dw;
          bfv[n] = *(const bf16x8*)(act_s + (((row * 34 + col) * 128 + ks * 64 + lg * 16) ^ ((col & 7) << 4)));
        }
#pragma unroll
        for (int m = 0; m < 4; ++m)
#pragma unroll
          for (int n = 0; n < 4; ++n)
            acc[m][n] = __builtin_amdgcn_mfma_f32_16x16x32_bf16(af[ks][m], bfv[n], acc[m][n], 0, 0, 0);
      }
      if (tap == 8 && cb < 4) {
        __syncthreads();       // all waves' act_s reads done
        stage_act(cb + 1);     // drains at next iteration's barrier A
      }
    }
  }

  const float scaleq = 0.07905694150420949f; // 160^-0.5
  int p_blk = xhat * 128;
#pragma unroll
  for (int m = 0; m < 4; ++m) {
#pragma unroll
    for (int n = 0; n < 4; ++n) {
#pragma unroll
      for (int r = 0; r < 4; ++r) {
        int co = co_blk + wco * 64 + m * 16 + lg * 4 + r;
        if (co >= FCO) continue;
        int p = p_blk + wp * 64 + n * 16 + lr;
        if (co < CO_) {
          float val = acc[m][n][r] + bias_c[co];
          size_t o = ((size_t)b * C_ + co) * HW_ + p;
          if (resid) val += resid[o];
          out[o] = (TO)val;
        } else {
          int qco = co - CO_;
          float val = acc[m][n][r] + bias_q[qco];
          if (qco < 640) {
            int nn = qco / DKH_, d = qco % DKH_;
            qt[(((size_t)b * NH_ + nn) * HW_ + p) * DKH_ + d] = (__bf16)(val * scaleq);
          } else if (qco < 1280) {
            int c2 = qco - 640;
            int nn = c2 / DKH_, d = c2 % DKH_;
            kt[(((size_t)b * NH_ + nn) * HW_ + p) * DKH_ + d] = (__bf16)val;
          } else {
            int c3 = qco - 1280;
            vt[((size_t)b * 64 + c3) * HW_ + p] = (__bf16)val;
          }
        }
      }
    }
  }
}

// ---------------------------------------------------------------------------
// Fused attention per (b, head, 16-query block) — flash-style local softmax.
// R16 VGPR DIET: (a) V loaded per PV-half (transient vfh[4], -32 persistent
// VGPR), (b) rel tables pre-converted to bf16 (direct bf16x8 loads, no cvt),
// (c) __launch_bounds__(256,4) pins VGPR <= 128 -> 4 blocks/CU residency.
// ---------------------------------------------------------------------------
__global__ __launch_bounds__(256, 4)
void attn_kernel(const __bf16* __restrict__ qt, const __bf16* __restrict__ kt,
                 const __bf16* __restrict__ vt, const __bf16* __restrict__ relwb,
                 const __bf16* __restrict__ relhb, __bf16* __restrict__ attn_out) {
  __shared__ float Rw_lds[16][66];
  __shared__ float Rh_lds[16][66];
  __shared__ __align__(16) __bf16 p_lds[4][16][136]; // per-wave P half, pad 8
  __shared__ float smax[16][4];
  __shared__ float ssum[16][4];
  __shared__ float part[4][16][16];

  int tid = threadIdx.x;
  int lane = tid & 63, wv = tid >> 6;
  int lr = lane & 15, lg = lane >> 4;

  int hw_lin = blockIdx.x + 64 * blockIdx.y + 256 * blockIdx.z;
  int xcd = hw_lin & 7, s = hw_lin >> 3;
  int qb = s & 63;
  int g = (s >> 6) * 8 + xcd;
  int n = g & 3, b = g >> 2;

  int p0 = qb * 16;
  const size_t qkbase = ((size_t)(b * NH_ + n)) * HW_ * DKH_;

  bf16x8 qf[5];
#pragma unroll
  for (int ks = 0; ks < 5; ++ks)
    qf[ks] = *(const bf16x8*)(qt + qkbase + (size_t)(p0 + lr) * DKH_ + ks * 32 + lg * 8);

  f32x4 zz = {0.f, 0.f, 0.f, 0.f};

  {
    int relpos = wv * 16 + lr;
    bool ok = relpos < 63;
    int rp = ok ? relpos : 0;
    f32x4 accw = zz, acch = zz;
#pragma unroll
    for (int ks = 0; ks < 5; ++ks) {
      bf16x8 bw = *(const bf16x8*)(relwb + (size_t)rp * DKH_ + ks * 32 + lg * 8);
      bf16x8 bh = *(const bf16x8*)(relhb + (size_t)rp * DKH_ + ks * 32 + lg * 8);
      if (!ok) { bw = bzero8(); bh = bzero8(); }
      accw = __builtin_amdgcn_mfma_f32_16x16x32_bf16(qf[ks], bw, accw, 0, 0, 0);
      acch = __builtin_amdgcn_mfma_f32_16x16x32_bf16(qf[ks], bh, acch, 0, 0, 0);
    }
#pragma unroll
    for (int r = 0; r < 4; ++r) {
      Rw_lds[lg * 4 + r][wv * 16 + lr] = accw[r];
      Rh_lds[lg * 4 + r][wv * 16 + lr] = acch[r];
    }
  }
  __syncthreads();   // barrier 1: Rw/Rh ready

  f32x4 acc[16];
#pragma unroll
  for (int t = 0; t < 16; ++t) acc[t] = zz;

  int key_base = wv * 256;
  __builtin_amdgcn_s_setprio(1);
#pragma unroll
  for (int t = 0; t < 16; ++t) {
    const __bf16* kp = kt + qkbase + (size_t)(key_base + t * 16 + lr) * DKH_ + lg * 8;
#pragma unroll
    for (int ks = 0; ks < 5; ++ks) {
      bf16x8 kf = *(const bf16x8*)(kp + ks * 32);
      acc[t] = __builtin_amdgcn_mfma_f32_16x16x32_bf16(qf[ks], kf, acc[t], 0, 0, 0);
    }
  }
  __builtin_amdgcn_s_setprio(0);

#pragma unroll
  for (int t = 0; t < 16; ++t) {
    int key = key_base + t * 16 + lr;
    int ky = key & 31, kx = key >> 5;
#pragma unroll
    for (int r = 0; r < 4; ++r) {
      int i = lg * 4 + r;
      int yi = (p0 + i) & 31, xi = (p0 + i) >> 5;
      acc[t][r] += Rw_lds[i][ky - yi + 31] + Rh_lds[i][kx - xi + 31];
    }
  }

  float mx[4];
#pragma unroll
  for (int r = 0; r < 4; ++r) {
    float m = acc[0][r];
#pragma unroll
    for (int t = 1; t < 16; ++t) m = fmaxf(m, acc[t][r]);
#pragma unroll
    for (int msk = 1; msk < 16; msk <<= 1)
      m = fmaxf(m, __shfl_xor(m, msk, 64));
    mx[r] = m;
  }
  if (lr == 0) {
#pragma unroll
    for (int r = 0; r < 4; ++r) smax[lg * 4 + r][wv] = mx[r];
  }

  // 2-pass exp + PV; V fragments loaded per half (transient registers),
  // issued BEFORE the exp loop so the loads land under the VALU work.
  const __bf16* vbase = vt + ((size_t)b * 64 + n * 16 + lr) * HW_ + key_base + lg * 8;
  float sm[4] = {0.f, 0.f, 0.f, 0.f};
  f32x4 pv_acc = zz;
#pragma unroll
  for (int half = 0; half < 2; ++half) {
    bf16x8 vfh[4];
#pragma unroll
    for (int ks = 0; ks < 4; ++ks)
      vfh[ks] = *(const bf16x8*)(vbase + (half * 4 + ks) * 32);
#pragma unroll
    for (int t = half * 8; t < half * 8 + 8; ++t) {
#pragma unroll
      for (int r = 0; r < 4; ++r) {
        float pv = __expf(acc[t][r] - mx[r]);
        __bf16 pb = (__bf16)pv;
        sm[r] += (float)pb;               // denominator consistent with bf16 P
        p_lds[wv][lg * 4 + r][(t & 7) * 16 + lr] = pb;
      }
    }
#pragma unroll
    for (int ks = 0; ks < 4; ++ks) {
      bf16x8 pf = *(const bf16x8*)&p_lds[wv][lr][ks * 32 + lg * 8];
      pv_acc = __builtin_amdgcn_mfma_f32_16x16x32_bf16(pf, vfh[ks], pv_acc, 0, 0, 0);
    }
  }
#pragma unroll
  for (int r = 0; r < 4; ++r) {
#pragma unroll
    for (int msk = 1; msk < 16; msk <<= 1)
      sm[r] += __shfl_xor(sm[r], msk, 64);
  }
  if (lr == 0) {
#pragma unroll
    for (int r = 0; r < 4; ++r) ssum[lg * 4 + r][wv] = sm[r];
  }

#pragma unroll
  for (int r = 0; r < 4; ++r) part[wv][lg * 4 + r][lr] = pv_acc[r];
  __syncthreads();   // barrier 2: part/smax/ssum ready

  int i = tid >> 4, dv = tid & 15;
  float m0 = smax[i][0], m1 = smax[i][1], m2 = smax[i][2], m3 = smax[i][3];
  float M = fmaxf(fmaxf(m0, m1), fmaxf(m2, m3));
  float e0 = __expf(m0 - M), e1 = __expf(m1 - M),
        e2 = __expf(m2 - M), e3 = __expf(m3 - M);
  float S = ssum[i][0] * e0 + ssum[i][1] * e1 + ssum[i][2] * e2 + ssum[i][3] * e3;
  float val = (part[0][i][dv] * e0 + part[1][i][dv] * e1 +
               part[2][i][dv] * e2 + part[3][i][dv] * e3) / S;
  int flat = (p0 + i) * 16 + dv;
  attn_out[((size_t)b * 64 + n * 16 + (flat >> 10)) * HW_ + (flat & 1023)] = (__bf16)val;
}

// ---------------------------------------------------------------------------
// 1x1 projection: blockIdx.y = 16-channel quarter -> 4x the blocks/waves.
// ---------------------------------------------------------------------------
template <typename TO>
__global__ __launch_bounds__(256)
void proj1x1(const __bf16* __restrict__ attn, const float* __restrict__ w,
             const float* __restrict__ bias, TO* __restrict__ out,
             const float* __restrict__ resid) {
  __shared__ float wl[16][64];
  int tid = threadIdx.x;
  int cq = blockIdx.y, b = blockIdx.z;
  int p = blockIdx.x * 256 + tid;
  for (int i = tid; i < 1024; i += 256)
    wl[i >> 6][i & 63] = w[(cq * 16 + (i >> 6)) * 64 + (i & 63)];
  __syncthreads();
  float in[64];
#pragma unroll
  for (int c = 0; c < 64; ++c) in[c] = (float)attn[((size_t)b * 64 + c) * HW_ + p];
#pragma unroll
  for (int c = 0; c < 16; ++c) {
    int gc = cq * 16 + c;
    float a = bias[gc];
#pragma unroll
    for (int cc = 0; cc < 64; ++cc) a += wl[c][cc] * in[cc];
    size_t o = ((size_t)b * C_ + 256 + gc) * HW_ + p;
    if (resid) a += resid[o];
    out[o] = (TO)a;
  }
}

// ---------------------------------------------------------------------------
extern "C" void kernel_launch(void* const* d_in, const int* in_sizes, int n_in,
                              void* d_out, int out_size, void* d_ws, size_t ws_size,
                              hipStream_t stream) {
  (void)in_sizes; (void)n_in; (void)out_size;
  const float* x = (const float*)d_in[0];
  const float* bn_g[2]   = {(const float*)d_in[1],  (const float*)d_in[5]};
  const float* bn_b[2]   = {(const float*)d_in[2],  (const float*)d_in[6]};
  const float* bn_m[2]   = {(const float*)d_in[3],  (const float*)d_in[7]};
  const float* bn_v[2]   = {(const float*)d_in[4],  (const float*)d_in[8]};
  const float* conv_w[2] = {(const float*)d_in[9],  (const float*)d_in[17]};
  const float* conv_b[2] = {(const float*)d_in[10], (const float*)d_in[18]};
  const float* qkv_w[2]  = {(const float*)d_in[11], (const float*)d_in[19]};
  const float* qkv_b[2]  = {(const float*)d_in[12], (const float*)d_in[20]};
  const float* attn_w[2] = {(const float*)d_in[13], (const float*)d_in[21]};
  const float* attn_b[2] = {(const float*)d_in[14], (const float*)d_in[22]};
  const float* rel_w[2]  = {(const float*)d_in[15], (const float*)d_in[23]};
  const float* rel_h[2]  = {(const float*)d_in[16], (const float*)d_in[24]};

  char* ws = (char*)d_ws;
  size_t off = 0;
  auto take = [&](size_t bytes) {
    char* p = ws + off;
    off += (bytes + 255) & ~(size_t)255;
    return p;
  };
  __bf16* y_nhwc = (__bf16*)take((size_t)B_ * HW_ * C_ * 2);         // 10.5 MB
  __bf16* qt     = (__bf16*)take((size_t)B_ * NH_ * HW_ * DKH_ * 2); // 21 MB
  __bf16* kt2    = (__bf16*)take((size_t)B_ * NH_ * HW_ * DKH_ * 2); // 21 MB
  __bf16* vt     = (__bf16*)take((size_t)B_ * 64 * HW_ * 2);         // 2 MB
  __bf16* attn_c = (__bf16*)take((size_t)B_ * 64 * HW_ * 2);         // 2 MB
  __bf16* l1out  = (__bf16*)take((size_t)B_ * C_ * HW_ * 2);         // 10.5 MB
  __bf16* wt_s   = (__bf16*)take((size_t)9 * FCO * C_ * 2);          // 9.2 MB (fused)
  __bf16* rel_wb = (__bf16*)take((size_t)63 * DKH_ * 2);             // 20 KB
  __bf16* rel_hb = (__bf16*)take((size_t)63 * DKH_ * 2);             // 20 KB
  if (ws_size < off) return;  // diagnostic: finite-error failure => ws too small

  for (int l = 0; l < 2; ++l) {
    const float* resid = (l == 0) ? nullptr : x;

    if (l == 0)
      bn_relu_t<float><<<dim3(32, 10, 16), dim3(32, 8), 0, stream>>>(
          x, bn_g[l], bn_b[l], bn_m[l], bn_v[l], y_nhwc);
    else
      bn_relu_t<__bf16><<<dim3(32, 10, 16), dim3(32, 8), 0, stream>>>(
          l1out, bn_g[l], bn_b[l], bn_m[l], bn_v[l], y_nhwc);

    transform_w2<<<(FCO * C_ + 255) / 256, 256, 0, stream>>>(conv_w[l], qkv_w[l], wt_s);
    transform_rel<<<(63 * DKH_ + 255) / 256, 256, 0, stream>>>(
        rel_w[l], rel_h[l], rel_wb, rel_hb);

    if (l == 0)
      conv3x3_fused<__bf16><<<dim3(8, 13, 16), 256, 0, stream>>>(
          y_nhwc, wt_s, conv_b[l], qkv_b[l], l1out, nullptr, qt, kt2, vt);
    else
      conv3x3_fused<float><<<dim3(8, 13, 16), 256, 0, stream>>>(
          y_nhwc, wt_s, conv_b[l], qkv_b[l], (float*)d_out, resid, qt, kt2, vt);

    attn_kernel<<<dim3(64, NH_, 16), 256, 0, stream>>>(
        qt, kt2, vt, rel_wb, rel_hb, attn_c);

    if (l == 0)
      proj1x1<__bf16><<<dim3(4, 4, 16), 256, 0, stream>>>(
          attn_c, attn_w[l], attn_b[l], l1out, nullptr);
    else
      proj1x1<float><<<dim3(4, 4, 16), 256, 0, stream>>>(
          attn_c, attn_w[l], attn_b[l], (float*)d_out, resid);
  }
}